// Round 10
// baseline (165.970 us; speedup 1.0000x reference)
//
#include <hip/hip_runtime.h>
#include <hip/hip_bf16.h>
#include <stdint.h>

typedef __hip_bfloat16 bf16;
typedef __attribute__((ext_vector_type(8))) __bf16 bf16x8;
typedef __attribute__((ext_vector_type(4))) float f32x4;

__device__ __forceinline__ bf16x8 load8bf(const bf16* p) {
    return __builtin_bit_cast(bf16x8, *(const int4*)p);
}

__device__ __forceinline__ void async16(const bf16* g, bf16* l) {
    __builtin_amdgcn_global_load_lds((const __attribute__((address_space(1))) void*)g,
                                     (__attribute__((address_space(3))) void*)l, 16, 0, 0);
}

// ---------------- cast x (f32 -> bf16), vectorized ----------------
__global__ __launch_bounds__(256) void cast_x_kernel(const float* __restrict__ in,
                                                     bf16* __restrict__ out, int n4) {
    int i = blockIdx.x * 256 + threadIdx.x;
    if (i >= n4) return;
    float4 v = ((const float4*)in)[i];
    ushort4 o;
    o.x = __builtin_bit_cast(unsigned short, __float2bfloat16(v.x));
    o.y = __builtin_bit_cast(unsigned short, __float2bfloat16(v.y));
    o.z = __builtin_bit_cast(unsigned short, __float2bfloat16(v.z));
    o.w = __builtin_bit_cast(unsigned short, __float2bfloat16(v.w));
    ((ushort4*)out)[i] = o;
}

// ---------------- transpose + cast: in f32 [R][C] -> out bf16 [C][R] ----------------
__global__ __launch_bounds__(256) void transpose_cast(const float* __restrict__ in,
                                                      bf16* __restrict__ out, int R, int C) {
    __shared__ float t[32][33];
    int c0 = blockIdx.x * 32, r0 = blockIdx.y * 32;
    int tx = threadIdx.x, ty = threadIdx.y;
#pragma unroll
    for (int j = 0; j < 32; j += 8)
        t[ty + j][tx] = in[(size_t)(r0 + ty + j) * C + c0 + tx];
    __syncthreads();
#pragma unroll
    for (int j = 0; j < 32; j += 8)
        out[(size_t)(c0 + ty + j) * R + r0 + tx] = __float2bfloat16(t[tx][ty + j]);
}

// ---------------- GEMM: C[M][N] = A[M][K] * Bt[N][K]^T, bf16 in, MFMA 16x16x32 ----------------
// R10 = R9 (counted-vmcnt depth-2 pipeline, BK=32, triple-buffered 48KB LDS, 3 blocks/CU)
// + sched_barrier(0) PINNING of the sync skeleton. R9's race: raw s_barrier has NO memory
// semantics in LLVM IR, so the global_load_lds stage could hoist above the WAR barrier
// (wave A stages buf[(t+2)%3] while wave B still reads it at iter t-1) -> sporadic stale
// K-slices (absmax 1.1e-2). Pins:
//   s_barrier; SB0  <- stage can't hoist above WAR barrier
//   stage;     SB0  <- stage can't sink below the counted vmcnt (count would be wrong)
//   vmcnt(N); s_barrier; SB0  <- ds_reads can't hoist into unsynced window
// Regions between pins (4 gloads | 8 ds_reads + 16 MFMA) remain freely schedulable.
template <int MODE>
__global__ __launch_bounds__(256, 3) void gemm_bt(
    const bf16* __restrict__ A, const bf16* __restrict__ Bt,
    int M, int N, int K,
    bf16* __restrict__ qo, bf16* __restrict__ ko, bf16* __restrict__ vto,
    float* __restrict__ out, const float* __restrict__ bias) {
    __shared__ __align__(16) bf16 A0[128 * 32];
    __shared__ __align__(16) bf16 B0[128 * 32];
    __shared__ __align__(16) bf16 A1[128 * 32];
    __shared__ __align__(16) bf16 B1[128 * 32];
    __shared__ __align__(16) bf16 A2[128 * 32];
    __shared__ __align__(16) bf16 B2[128 * 32];
    const int tid = threadIdx.x;
    const int l = tid & 63, wid = tid >> 6;
    const int lo = l & 15, hi = l >> 4;
    const int wm = wid >> 1, wn = wid & 1;
    const int m0 = blockIdx.x * 128, n0 = blockIdx.y * 128;
    const int tsr = tid >> 2;                       // staging row 0..63 (also +64)
    const int tsc = tid & 3;                        // 16B chunk
    const int csw = ((tsc ^ (tsr & 3)) * 8);        // pre-swizzled global col (elems)
    const int cl  = tsc * 8;                        // linear LDS col (elems)
    const int colr = ((hi ^ (lo & 3)) * 8);         // swizzled fragment read col

    f32x4 acc[4][4];
#pragma unroll
    for (int i = 0; i < 4; ++i)
#pragma unroll
        for (int j = 0; j < 4; ++j) acc[i][j] = f32x4{0.f, 0.f, 0.f, 0.f};

#define STAGE32(AD, BD, KT)                                                           \
    {                                                                                 \
        async16(A + (size_t)(m0 + tsr) * K + (KT) * 32 + csw, (AD) + tsr * 32 + cl);  \
        async16(A + (size_t)(m0 + 64 + tsr) * K + (KT) * 32 + csw,                    \
                (AD) + (64 + tsr) * 32 + cl);                                         \
        async16(Bt + (size_t)(n0 + tsr) * K + (KT) * 32 + csw, (BD) + tsr * 32 + cl); \
        async16(Bt + (size_t)(n0 + 64 + tsr) * K + (KT) * 32 + csw,                   \
                (BD) + (64 + tsr) * 32 + cl);                                         \
    }

#define KB(AC, BC, AS, BS, KT, STG, WAITASM)                                          \
    {                                                                                 \
        __builtin_amdgcn_s_barrier();          /* ends reads of AS/BS old contents */ \
        __builtin_amdgcn_sched_barrier(0);     /* stage can't hoist above barrier */  \
        if (STG) STAGE32(AS, BS, (KT) + 2)                                            \
        __builtin_amdgcn_sched_barrier(0);     /* stage can't sink below vmcnt */     \
        asm volatile(WAITASM ::: "memory");                                           \
        __builtin_amdgcn_s_barrier();          /* all waves' tile-KT loads landed */  \
        __builtin_amdgcn_sched_barrier(0);     /* reads can't hoist above barrier */  \
        bf16x8 af[4], bf_[4];                                                         \
        _Pragma("unroll") for (int mt = 0; mt < 4; ++mt)                              \
            af[mt] = load8bf((AC) + (wm * 64 + mt * 16 + lo) * 32 + colr);            \
        _Pragma("unroll") for (int nt = 0; nt < 4; ++nt)                              \
            bf_[nt] = load8bf((BC) + (wn * 64 + nt * 16 + lo) * 32 + colr);           \
        _Pragma("unroll") for (int mt = 0; mt < 4; ++mt)                              \
            _Pragma("unroll") for (int nt = 0; nt < 4; ++nt)                          \
                acc[mt][nt] = __builtin_amdgcn_mfma_f32_16x16x32_bf16(                \
                    af[mt], bf_[nt], acc[mt][nt], 0, 0, 0);                           \
    }

    const int nkt = K / 32;  // 32 for K=1024
    STAGE32(A0, B0, 0)
    STAGE32(A1, B1, 1)
    for (int kt = 0; kt + 5 < nkt; kt += 3) {
        KB(A0, B0, A2, B2, kt, true, "s_waitcnt vmcnt(8)")
        KB(A1, B1, A0, B0, kt + 1, true, "s_waitcnt vmcnt(8)")
        KB(A2, B2, A1, B1, kt + 2, true, "s_waitcnt vmcnt(8)")
    }
    // nkt = 32: loop covered t=0..26 (stages through 28); tail t=27..31
    KB(A0, B0, A2, B2, 27, true, "s_waitcnt vmcnt(8)")   // stage 29 -> buf2
    KB(A1, B1, A0, B0, 28, true, "s_waitcnt vmcnt(8)")   // stage 30 -> buf0
    KB(A2, B2, A1, B1, 29, true, "s_waitcnt vmcnt(8)")   // stage 31 -> buf1
    KB(A0, B0, A2, B2, 30, false, "s_waitcnt vmcnt(4)")  // leave 31's 4 in flight
    KB(A1, B1, A2, B2, 31, false, "s_waitcnt vmcnt(0)")  // final drain
#undef KB
#undef STAGE32

#pragma unroll
    for (int mt = 0; mt < 4; ++mt)
#pragma unroll
        for (int nt = 0; nt < 4; ++nt)
#pragma unroll
            for (int r = 0; r < 4; ++r) {
                int row = m0 + wm * 64 + mt * 16 + hi * 4 + r;
                int col = n0 + wn * 64 + nt * 16 + lo;
                float v = acc[mt][nt][r];
                if (MODE == 0) {
                    if (col < 1024) {
                        qo[(size_t)row * 1024 + col] = __float2bfloat16(v * 0.125f);
                    } else if (col < 2048) {
                        ko[(size_t)row * 1024 + (col - 1024)] = __float2bfloat16(v);
                    } else {
                        int c = col - 2048;  // = h*64+d
                        vto[((size_t)(row >> 10) * 1024 + c) * 1024 + (row & 1023)] = __float2bfloat16(v);
                    }
                } else {
                    out[(size_t)row * N + col] = v + bias[col];
                }
            }
}

// ---------------- flash attention: grid = B*H*(N/128), 4 waves, 32 q-rows/wave ----------------
// (unchanged from R8: gload_lds double-buffer, XOR swizzle, no-max softmax, deferred l-sum)
__global__ __launch_bounds__(256, 3) void flash_attn(
    const bf16* __restrict__ q,    // [B*N][1024], q pre-scaled by 1/8
    const bf16* __restrict__ kin,  // [B*N][1024]
    const bf16* __restrict__ vt,   // [(b*1024 + h*64 + d)][1024] tokens
    bf16* __restrict__ out)        // [B*N][1024]
{
    __shared__ __align__(16) bf16 Kl0[64 * 64];
    __shared__ __align__(16) bf16 Vl0[64 * 64];
    __shared__ __align__(16) bf16 Kl1[64 * 64];
    __shared__ __align__(16) bf16 Vl1[64 * 64];
    __shared__ __align__(16) bf16 Pl[4 * 32 * 72];
    const int tid = threadIdx.x;
    const int l = tid & 63, w = tid >> 6;
    const int lo = l & 15, hi = l >> 4;
    const int bid = (blockIdx.x & 7) * 128 + (blockIdx.x >> 3);
    const int qt = bid & 7, h = (bid >> 3) & 15, b = bid >> 7;
    const int ts_r = tid >> 3;
    const int ts_c = tid & 7;
    const int ts_csw = (ts_c ^ (ts_r & 7)) * 8;
    const int ts_lds = tid * 8;

    const bf16* kbase = kin + (size_t)(b * 1024) * 1024 + h * 64;
    const bf16* vbase = vt + (size_t)(b * 1024 + h * 64) * 1024;

#define STAGE_KV(KD, VD, KT)                                                          \
    {                                                                                 \
        async16(kbase + (size_t)((KT) * 64 + ts_r) * 1024 + ts_csw, (KD) + ts_lds);   \
        async16(kbase + (size_t)((KT) * 64 + 32 + ts_r) * 1024 + ts_csw,              \
                (KD) + 2048 + ts_lds);                                                \
        async16(vbase + (size_t)ts_r * 1024 + (KT) * 64 + ts_csw, (VD) + ts_lds);     \
        async16(vbase + (size_t)(32 + ts_r) * 1024 + (KT) * 64 + ts_csw,              \
                (VD) + 2048 + ts_lds);                                                \
    }

    bf16x8 qf[2][2];
#pragma unroll
    for (int mt = 0; mt < 2; ++mt)
#pragma unroll
        for (int ks = 0; ks < 2; ++ks) {
            int tok = qt * 128 + w * 32 + mt * 16 + lo;
            qf[mt][ks] = load8bf(q + (size_t)(b * 1024 + tok) * 1024 + h * 64 + ks * 32 + hi * 8);
        }

    float lsum[2][4];
    f32x4 oacc[2][4];
#pragma unroll
    for (int mt = 0; mt < 2; ++mt)
#pragma unroll
        for (int r = 0; r < 4; ++r) lsum[mt][r] = 0.f;
#pragma unroll
    for (int mt = 0; mt < 2; ++mt)
#pragma unroll
        for (int nt = 0; nt < 4; ++nt) oacc[mt][nt] = f32x4{0.f, 0.f, 0.f, 0.f};

    STAGE_KV(Kl0, Vl0, 0)
    __syncthreads();

#define FA_ITER(KC, VC, KN, VN, KT, STG)                                              \
    {                                                                                 \
        if (STG) { STAGE_KV(KN, VN, (KT) + 1) }                                       \
        __builtin_amdgcn_sched_barrier(0);                                            \
        f32x4 s[2][4];                                                                \
        _Pragma("unroll") for (int mt = 0; mt < 2; ++mt)                              \
            _Pragma("unroll") for (int nt = 0; nt < 4; ++nt)                          \
                s[mt][nt] = f32x4{0.f, 0.f, 0.f, 0.f};                                \
        _Pragma("unroll") for (int ks = 0; ks < 2; ++ks) {                            \
            bf16x8 kf[4];                                                             \
            _Pragma("unroll") for (int nt = 0; nt < 4; ++nt) {                        \
                int kr = nt * 16 + lo;                                                \
                kf[nt] = load8bf((KC) + kr * 64 + ((ks * 32 + hi * 8) ^ ((kr & 7) * 8))); \
            }                                                                         \
            _Pragma("unroll") for (int mt = 0; mt < 2; ++mt)                          \
                _Pragma("unroll") for (int nt = 0; nt < 4; ++nt)                      \
                    s[mt][nt] = __builtin_amdgcn_mfma_f32_16x16x32_bf16(              \
                        qf[mt][ks], kf[nt], s[mt][nt], 0, 0, 0);                      \
        }                                                                             \
        _Pragma("unroll") for (int mt = 0; mt < 2; ++mt)                              \
            _Pragma("unroll") for (int nt = 0; nt < 4; ++nt)                          \
                _Pragma("unroll") for (int r = 0; r < 4; ++r) {                       \
                    float p = __expf(s[mt][nt][r]);                                   \
                    lsum[mt][r] += p;                                                 \
                    Pl[(w * 32 + mt * 16 + hi * 4 + r) * 72 + nt * 16 + lo] =         \
                        __float2bfloat16(p);                                          \
                }                                                                     \
        _Pragma("unroll") for (int ks = 0; ks < 2; ++ks) {                            \
            bf16x8 vf[4], pf[2];                                                      \
            _Pragma("unroll") for (int nt = 0; nt < 4; ++nt) {                        \
                int vr = nt * 16 + lo;                                                \
                vf[nt] = load8bf((VC) + vr * 64 + ((ks * 32 + hi * 8) ^ ((vr & 7) * 8))); \
            }                                                                         \
            _Pragma("unroll") for (int mt = 0; mt < 2; ++mt)                          \
                pf[mt] = load8bf(Pl + (w * 32 + mt * 16 + lo) * 72 + ks * 32 + hi * 8); \
            _Pragma("unroll") for (int mt = 0; mt < 2; ++mt)                          \
                _Pragma("unroll") for (int nt = 0; nt < 4; ++nt)                      \
                    oacc[mt][nt] = __builtin_amdgcn_mfma_f32_16x16x32_bf16(           \
                        pf[mt], vf[nt], oacc[mt][nt], 0, 0, 0);                       \
        }                                                                             \
        __syncthreads();                                                              \
    }

    for (int kt = 0; kt < 16; kt += 2) {
        FA_ITER(Kl0, Vl0, Kl1, Vl1, kt, true)
        FA_ITER(Kl1, Vl1, Kl0, Vl0, kt + 1, (kt + 2 < 16))
    }
#undef FA_ITER
#undef STAGE_KV

#pragma unroll
    for (int mt = 0; mt < 2; ++mt)
#pragma unroll
        for (int r = 0; r < 4; ++r) {
#pragma unroll
            for (int off = 1; off < 16; off <<= 1)
                lsum[mt][r] += __shfl_xor(lsum[mt][r], off);
        }

#pragma unroll
    for (int mt = 0; mt < 2; ++mt)
#pragma unroll
        for (int nt = 0; nt < 4; ++nt)
#pragma unroll
            for (int r = 0; r < 4; ++r) {
                int tok = qt * 128 + w * 32 + mt * 16 + hi * 4 + r;
                int d = nt * 16 + lo;
                out[(size_t)(b * 1024 + tok) * 1024 + h * 64 + d] =
                    __float2bfloat16(oacc[mt][nt][r] / lsum[mt][r]);
            }
}

extern "C" void kernel_launch(void* const* d_in, const int* in_sizes, int n_in,
                              void* d_out, int out_size, void* d_ws, size_t ws_size,
                              hipStream_t stream) {
    const float* x      = (const float*)d_in[0];
    const float* w_qkv  = (const float*)d_in[1];
    const float* w_proj = (const float*)d_in[2];
    const float* b_proj = (const float*)d_in[3];
    float* out = (float*)d_out;   // reference output dtype is float32

    char* ws = (char*)d_ws;
    bf16* xb     = (bf16*)(ws);                       // 16 MB [8192][1024]; reused as attn out
    bf16* wqkvT  = (bf16*)(ws + (16ull << 20));       //  6 MB [3072][1024]
    bf16* wprojT = (bf16*)(ws + (22ull << 20));       //  2 MB [1024][1024]
    bf16* qb     = (bf16*)(ws + (24ull << 20));       // 16 MB
    bf16* kb     = (bf16*)(ws + (40ull << 20));       // 16 MB
    bf16* vtb    = (bf16*)(ws + (56ull << 20));       // 16 MB  [b*1024 + h*64+d][1024]
    bf16* attn   = xb;                                // reuse (xb dead after QKV GEMM)

    cast_x_kernel<<<8192, 256, 0, stream>>>(x, xb, 2 * 1024 * 1024);
    transpose_cast<<<dim3(96, 32), dim3(32, 8), 0, stream>>>(w_qkv, wqkvT, 1024, 3072);
    transpose_cast<<<dim3(32, 32), dim3(32, 8), 0, stream>>>(w_proj, wprojT, 1024, 1024);
    gemm_bt<0><<<dim3(64, 24), 256, 0, stream>>>(xb, wqkvT, 8192, 3072, 1024,
                                                 qb, kb, vtb, nullptr, nullptr);
    flash_attn<<<1024, 256, 0, stream>>>(qb, kb, vtb, attn);
    gemm_bt<1><<<dim3(64, 8), 256, 0, stream>>>(attn, wprojT, 8192, 1024, 1024,
                                                nullptr, nullptr, nullptr, out, b_proj);
}

// Round 11
// 165.028 us; speedup vs baseline: 1.0057x; 1.0057x over previous
//
#include <hip/hip_runtime.h>
#include <hip/hip_bf16.h>
#include <stdint.h>

typedef __hip_bfloat16 bf16;
typedef __attribute__((ext_vector_type(8))) __bf16 bf16x8;
typedef __attribute__((ext_vector_type(4))) float f32x4;

__device__ __forceinline__ bf16x8 load8bf(const bf16* p) {
    return __builtin_bit_cast(bf16x8, *(const int4*)p);
}

__device__ __forceinline__ void async16(const bf16* g, bf16* l) {
    __builtin_amdgcn_global_load_lds((const __attribute__((address_space(1))) void*)g,
                                     (__attribute__((address_space(3))) void*)l, 16, 0, 0);
}

// ---------------- cast x (f32 -> bf16), vectorized ----------------
__global__ __launch_bounds__(256) void cast_x_kernel(const float* __restrict__ in,
                                                     bf16* __restrict__ out, int n4) {
    int i = blockIdx.x * 256 + threadIdx.x;
    if (i >= n4) return;
    float4 v = ((const float4*)in)[i];
    ushort4 o;
    o.x = __builtin_bit_cast(unsigned short, __float2bfloat16(v.x));
    o.y = __builtin_bit_cast(unsigned short, __float2bfloat16(v.y));
    o.z = __builtin_bit_cast(unsigned short, __float2bfloat16(v.z));
    o.w = __builtin_bit_cast(unsigned short, __float2bfloat16(v.w));
    ((ushort4*)out)[i] = o;
}

// ---------------- transpose + cast: in f32 [R][C] -> out bf16 [C][R] ----------------
__global__ __launch_bounds__(256) void transpose_cast(const float* __restrict__ in,
                                                      bf16* __restrict__ out, int R, int C) {
    __shared__ float t[32][33];
    int c0 = blockIdx.x * 32, r0 = blockIdx.y * 32;
    int tx = threadIdx.x, ty = threadIdx.y;
#pragma unroll
    for (int j = 0; j < 32; j += 8)
        t[ty + j][tx] = in[(size_t)(r0 + ty + j) * C + c0 + tx];
    __syncthreads();
#pragma unroll
    for (int j = 0; j < 32; j += 8)
        out[(size_t)(c0 + ty + j) * R + r0 + tx] = __float2bfloat16(t[tx][ty + j]);
}

// ---------------- GEMM: C[M][N] = A[M][K] * Bt[N][K]^T, bf16 in, MFMA 16x16x32 ----------------
// MODE 0: QKV epilogue (split q/k/v, q*=0.125, v transposed).  MODE 1: +bias, f32 out.
// R11: R8's structure (syncthreads dbuf, stage-early / drain-at-next-barrier, 1 barrier/tile)
// at BK=32: 4 x 8KB = 32KB LDS + launch_bounds(256,4) -> 4-5 blocks/CU (16-20 waves) vs R8's 2.
// Occupancy is the lever (R8: 20.6% occ, MfmaUtil 21%; m97 got 37% MfmaUtil at 3 blocks/CU —
// wave TLP absorbs the barrier drain, m114). R10's counted-vmcnt pipeline REGRESSED (103 vs 97:
// 4x barrier rate + 4-way read conflicts) and is abandoned.
// BK=32 swizzle derivation: rows are 64B (4 x 16B chunks), so row parity alternates bank halves;
// XOR chunk with ((row>>1)&3) spreads the 4 chunks across each half -> exactly 2-way = free
// (R10's (row&3) left rows =0 mod 4 colliding 4-way: 6.3e6 conflicts observed).
template <int MODE>
__global__ __launch_bounds__(256, 4) void gemm_bt(
    const bf16* __restrict__ A, const bf16* __restrict__ Bt,
    int M, int N, int K,
    bf16* __restrict__ qo, bf16* __restrict__ ko, bf16* __restrict__ vto,
    float* __restrict__ out, const float* __restrict__ bias) {
    __shared__ __align__(16) bf16 A0[128 * 32];
    __shared__ __align__(16) bf16 B0[128 * 32];
    __shared__ __align__(16) bf16 A1[128 * 32];
    __shared__ __align__(16) bf16 B1[128 * 32];
    const int tid = threadIdx.x;
    const int l = tid & 63, wid = tid >> 6;
    const int lo = l & 15, hi = l >> 4;
    const int wm = wid >> 1, wn = wid & 1;
    const int m0 = blockIdx.x * 128, n0 = blockIdx.y * 128;
    const int tsr = tid >> 2;                         // staging rows {tsr, tsr+64}
    const int tsc = tid & 3;                          // 16B chunk
    const int csw = (tsc ^ ((tsr >> 1) & 3)) * 8;     // pre-swizzled global col (elems)
    const int cl  = tsc * 8;                          // linear LDS col (elems)

    f32x4 acc[4][4];
#pragma unroll
    for (int i = 0; i < 4; ++i)
#pragma unroll
        for (int j = 0; j < 4; ++j) acc[i][j] = f32x4{0.f, 0.f, 0.f, 0.f};

#define STAGE32(AD, BD, KT)                                                           \
    {                                                                                 \
        async16(A + (size_t)(m0 + tsr) * K + (KT) * 32 + csw, (AD) + tsr * 32 + cl);  \
        async16(A + (size_t)(m0 + 64 + tsr) * K + (KT) * 32 + csw,                    \
                (AD) + (64 + tsr) * 32 + cl);                                         \
        async16(Bt + (size_t)(n0 + tsr) * K + (KT) * 32 + csw, (BD) + tsr * 32 + cl); \
        async16(Bt + (size_t)(n0 + 64 + tsr) * K + (KT) * 32 + csw,                   \
                (BD) + (64 + tsr) * 32 + cl);                                         \
    }

// one K-tile (BK=32): barrier (drains prev-iter stage + ends reads of the buffer being
// overwritten next), stage KT+1, then 8 ds_read_b128 + 16 MFMA from current buffer.
#define KB32(AC, BC, AS, BS, KT, STG)                                                 \
    {                                                                                 \
        __syncthreads();                                                              \
        if (STG) STAGE32(AS, BS, (KT) + 1)                                            \
        __builtin_amdgcn_sched_barrier(0);                                            \
        bf16x8 af[4], bf_[4];                                                         \
        _Pragma("unroll") for (int mt = 0; mt < 4; ++mt) {                            \
            int ar = wm * 64 + mt * 16 + lo;                                          \
            af[mt] = load8bf((AC) + ar * 32 + ((hi ^ ((ar >> 1) & 3)) * 8));          \
        }                                                                             \
        _Pragma("unroll") for (int nt = 0; nt < 4; ++nt) {                            \
            int br = wn * 64 + nt * 16 + lo;                                          \
            bf_[nt] = load8bf((BC) + br * 32 + ((hi ^ ((br >> 1) & 3)) * 8));         \
        }                                                                             \
        _Pragma("unroll") for (int mt = 0; mt < 4; ++mt)                              \
            _Pragma("unroll") for (int nt = 0; nt < 4; ++nt)                          \
                acc[mt][nt] = __builtin_amdgcn_mfma_f32_16x16x32_bf16(                \
                    af[mt], bf_[nt], acc[mt][nt], 0, 0, 0);                           \
    }

    const int nkt = K / 32;  // 32 for K=1024 (even)
    STAGE32(A0, B0, 0)
    for (int kt = 0; kt < nkt; kt += 2) {
        KB32(A0, B0, A1, B1, kt, true)                     // stage kt+1 (always valid)
        KB32(A1, B1, A0, B0, kt + 1, (kt + 2 < nkt))       // stage kt+2 if it exists
    }
#undef KB32
#undef STAGE32

#pragma unroll
    for (int mt = 0; mt < 4; ++mt)
#pragma unroll
        for (int nt = 0; nt < 4; ++nt)
#pragma unroll
            for (int r = 0; r < 4; ++r) {
                int row = m0 + wm * 64 + mt * 16 + hi * 4 + r;
                int col = n0 + wn * 64 + nt * 16 + lo;
                float v = acc[mt][nt][r];
                if (MODE == 0) {
                    if (col < 1024) {
                        qo[(size_t)row * 1024 + col] = __float2bfloat16(v * 0.125f);
                    } else if (col < 2048) {
                        ko[(size_t)row * 1024 + (col - 1024)] = __float2bfloat16(v);
                    } else {
                        int c = col - 2048;  // = h*64+d
                        vto[((size_t)(row >> 10) * 1024 + c) * 1024 + (row & 1023)] = __float2bfloat16(v);
                    }
                } else {
                    out[(size_t)row * N + col] = v + bias[col];
                }
            }
}

// ---------------- flash attention: grid = B*H*(N/128), 4 waves, 32 q-rows/wave ----------------
// (unchanged from R8: gload_lds double-buffer, XOR swizzle, no-max softmax, deferred l-sum)
__global__ __launch_bounds__(256, 3) void flash_attn(
    const bf16* __restrict__ q,    // [B*N][1024], q pre-scaled by 1/8
    const bf16* __restrict__ kin,  // [B*N][1024]
    const bf16* __restrict__ vt,   // [(b*1024 + h*64 + d)][1024] tokens
    bf16* __restrict__ out)        // [B*N][1024]
{
    __shared__ __align__(16) bf16 Kl0[64 * 64];
    __shared__ __align__(16) bf16 Vl0[64 * 64];
    __shared__ __align__(16) bf16 Kl1[64 * 64];
    __shared__ __align__(16) bf16 Vl1[64 * 64];
    __shared__ __align__(16) bf16 Pl[4 * 32 * 72];
    const int tid = threadIdx.x;
    const int l = tid & 63, w = tid >> 6;
    const int lo = l & 15, hi = l >> 4;
    const int bid = (blockIdx.x & 7) * 128 + (blockIdx.x >> 3);
    const int qt = bid & 7, h = (bid >> 3) & 15, b = bid >> 7;
    const int ts_r = tid >> 3;
    const int ts_c = tid & 7;
    const int ts_csw = (ts_c ^ (ts_r & 7)) * 8;
    const int ts_lds = tid * 8;

    const bf16* kbase = kin + (size_t)(b * 1024) * 1024 + h * 64;
    const bf16* vbase = vt + (size_t)(b * 1024 + h * 64) * 1024;

#define STAGE_KV(KD, VD, KT)                                                          \
    {                                                                                 \
        async16(kbase + (size_t)((KT) * 64 + ts_r) * 1024 + ts_csw, (KD) + ts_lds);   \
        async16(kbase + (size_t)((KT) * 64 + 32 + ts_r) * 1024 + ts_csw,              \
                (KD) + 2048 + ts_lds);                                                \
        async16(vbase + (size_t)ts_r * 1024 + (KT) * 64 + ts_csw, (VD) + ts_lds);     \
        async16(vbase + (size_t)(32 + ts_r) * 1024 + (KT) * 64 + ts_csw,              \
                (VD) + 2048 + ts_lds);                                                \
    }

    bf16x8 qf[2][2];
#pragma unroll
    for (int mt = 0; mt < 2; ++mt)
#pragma unroll
        for (int ks = 0; ks < 2; ++ks) {
            int tok = qt * 128 + w * 32 + mt * 16 + lo;
            qf[mt][ks] = load8bf(q + (size_t)(b * 1024 + tok) * 1024 + h * 64 + ks * 32 + hi * 8);
        }

    float lsum[2][4];
    f32x4 oacc[2][4];
#pragma unroll
    for (int mt = 0; mt < 2; ++mt)
#pragma unroll
        for (int r = 0; r < 4; ++r) lsum[mt][r] = 0.f;
#pragma unroll
    for (int mt = 0; mt < 2; ++mt)
#pragma unroll
        for (int nt = 0; nt < 4; ++nt) oacc[mt][nt] = f32x4{0.f, 0.f, 0.f, 0.f};

    STAGE_KV(Kl0, Vl0, 0)
    __syncthreads();

#define FA_ITER(KC, VC, KN, VN, KT, STG)                                              \
    {                                                                                 \
        if (STG) { STAGE_KV(KN, VN, (KT) + 1) }                                       \
        __builtin_amdgcn_sched_barrier(0);                                            \
        f32x4 s[2][4];                                                                \
        _Pragma("unroll") for (int mt = 0; mt < 2; ++mt)                              \
            _Pragma("unroll") for (int nt = 0; nt < 4; ++nt)                          \
                s[mt][nt] = f32x4{0.f, 0.f, 0.f, 0.f};                                \
        _Pragma("unroll") for (int ks = 0; ks < 2; ++ks) {                            \
            bf16x8 kf[4];                                                             \
            _Pragma("unroll") for (int nt = 0; nt < 4; ++nt) {                        \
                int kr = nt * 16 + lo;                                                \
                kf[nt] = load8bf((KC) + kr * 64 + ((ks * 32 + hi * 8) ^ ((kr & 7) * 8))); \
            }                                                                         \
            _Pragma("unroll") for (int mt = 0; mt < 2; ++mt)                          \
                _Pragma("unroll") for (int nt = 0; nt < 4; ++nt)                      \
                    s[mt][nt] = __builtin_amdgcn_mfma_f32_16x16x32_bf16(              \
                        qf[mt][ks], kf[nt], s[mt][nt], 0, 0, 0);                      \
        }                                                                             \
        _Pragma("unroll") for (int mt = 0; mt < 2; ++mt)                              \
            _Pragma("unroll") for (int nt = 0; nt < 4; ++nt)                          \
                _Pragma("unroll") for (int r = 0; r < 4; ++r) {                       \
                    float p = __expf(s[mt][nt][r]);                                   \
                    lsum[mt][r] += p;                                                 \
                    Pl[(w * 32 + mt * 16 + hi * 4 + r) * 72 + nt * 16 + lo] =         \
                        __float2bfloat16(p);                                          \
                }                                                                     \
        _Pragma("unroll") for (int ks = 0; ks < 2; ++ks) {                            \
            bf16x8 vf[4], pf[2];                                                      \
            _Pragma("unroll") for (int nt = 0; nt < 4; ++nt) {                        \
                int vr = nt * 16 + lo;                                                \
                vf[nt] = load8bf((VC) + vr * 64 + ((ks * 32 + hi * 8) ^ ((vr & 7) * 8))); \
            }                                                                         \
            _Pragma("unroll") for (int mt = 0; mt < 2; ++mt)                          \
                pf[mt] = load8bf(Pl + (w * 32 + mt * 16 + lo) * 72 + ks * 32 + hi * 8); \
            _Pragma("unroll") for (int mt = 0; mt < 2; ++mt)                          \
                _Pragma("unroll") for (int nt = 0; nt < 4; ++nt)                      \
                    oacc[mt][nt] = __builtin_amdgcn_mfma_f32_16x16x32_bf16(           \
                        pf[mt], vf[nt], oacc[mt][nt], 0, 0, 0);                       \
        }                                                                             \
        __syncthreads();                                                              \
    }

    for (int kt = 0; kt < 16; kt += 2) {
        FA_ITER(Kl0, Vl0, Kl1, Vl1, kt, true)
        FA_ITER(Kl1, Vl1, Kl0, Vl0, kt + 1, (kt + 2 < 16))
    }
#undef FA_ITER
#undef STAGE_KV

#pragma unroll
    for (int mt = 0; mt < 2; ++mt)
#pragma unroll
        for (int r = 0; r < 4; ++r) {
#pragma unroll
            for (int off = 1; off < 16; off <<= 1)
                lsum[mt][r] += __shfl_xor(lsum[mt][r], off);
        }

#pragma unroll
    for (int mt = 0; mt < 2; ++mt)
#pragma unroll
        for (int nt = 0; nt < 4; ++nt)
#pragma unroll
            for (int r = 0; r < 4; ++r) {
                int tok = qt * 128 + w * 32 + mt * 16 + hi * 4 + r;
                int d = nt * 16 + lo;
                out[(size_t)(b * 1024 + tok) * 1024 + h * 64 + d] =
                    __float2bfloat16(oacc[mt][nt][r] / lsum[mt][r]);
            }
}

extern "C" void kernel_launch(void* const* d_in, const int* in_sizes, int n_in,
                              void* d_out, int out_size, void* d_ws, size_t ws_size,
                              hipStream_t stream) {
    const float* x      = (const float*)d_in[0];
    const float* w_qkv  = (const float*)d_in[1];
    const float* w_proj = (const float*)d_in[2];
    const float* b_proj = (const float*)d_in[3];
    float* out = (float*)d_out;   // reference output dtype is float32

    char* ws = (char*)d_ws;
    bf16* xb     = (bf16*)(ws);                       // 16 MB [8192][1024]; reused as attn out
    bf16* wqkvT  = (bf16*)(ws + (16ull << 20));       //  6 MB [3072][1024]
    bf16* wprojT = (bf16*)(ws + (22ull << 20));       //  2 MB [1024][1024]
    bf16* qb     = (bf16*)(ws + (24ull << 20));       // 16 MB
    bf16* kb     = (bf16*)(ws + (40ull << 20));       // 16 MB
    bf16* vtb    = (bf16*)(ws + (56ull << 20));       // 16 MB  [b*1024 + h*64+d][1024]
    bf16* attn   = xb;                                // reuse (xb dead after QKV GEMM)

    cast_x_kernel<<<8192, 256, 0, stream>>>(x, xb, 2 * 1024 * 1024);
    transpose_cast<<<dim3(96, 32), dim3(32, 8), 0, stream>>>(w_qkv, wqkvT, 1024, 3072);
    transpose_cast<<<dim3(32, 32), dim3(32, 8), 0, stream>>>(w_proj, wprojT, 1024, 1024);
    gemm_bt<0><<<dim3(64, 24), 256, 0, stream>>>(xb, wqkvT, 8192, 3072, 1024,
                                                 qb, kb, vtb, nullptr, nullptr);
    flash_attn<<<1024, 256, 0, stream>>>(qb, kb, vtb, attn);
    gemm_bt<1><<<dim3(64, 8), 256, 0, stream>>>(attn, wprojT, 8192, 1024, 1024,
                                                nullptr, nullptr, nullptr, out, b_proj);
}

// Round 12
// 162.327 us; speedup vs baseline: 1.0224x; 1.0166x over previous
//
#include <hip/hip_runtime.h>
#include <hip/hip_bf16.h>
#include <stdint.h>

typedef __hip_bfloat16 bf16;
typedef __attribute__((ext_vector_type(8))) __bf16 bf16x8;
typedef __attribute__((ext_vector_type(4))) float f32x4;

__device__ __forceinline__ bf16x8 load8bf(const bf16* p) {
    return __builtin_bit_cast(bf16x8, *(const int4*)p);
}

__device__ __forceinline__ void async16(const bf16* g, bf16* l) {
    __builtin_amdgcn_global_load_lds((const __attribute__((address_space(1))) void*)g,
                                     (__attribute__((address_space(3))) void*)l, 16, 0, 0);
}

// ---------------- cast x (f32 -> bf16), vectorized ----------------
__global__ __launch_bounds__(256) void cast_x_kernel(const float* __restrict__ in,
                                                     bf16* __restrict__ out, int n4) {
    int i = blockIdx.x * 256 + threadIdx.x;
    if (i >= n4) return;
    float4 v = ((const float4*)in)[i];
    ushort4 o;
    o.x = __builtin_bit_cast(unsigned short, __float2bfloat16(v.x));
    o.y = __builtin_bit_cast(unsigned short, __float2bfloat16(v.y));
    o.z = __builtin_bit_cast(unsigned short, __float2bfloat16(v.z));
    o.w = __builtin_bit_cast(unsigned short, __float2bfloat16(v.w));
    ((ushort4*)out)[i] = o;
}

// ---------------- transpose + cast: in f32 [R][C] -> out bf16 [C][R] ----------------
__global__ __launch_bounds__(256) void transpose_cast(const float* __restrict__ in,
                                                      bf16* __restrict__ out, int R, int C) {
    __shared__ float t[32][33];
    int c0 = blockIdx.x * 32, r0 = blockIdx.y * 32;
    int tx = threadIdx.x, ty = threadIdx.y;
#pragma unroll
    for (int j = 0; j < 32; j += 8)
        t[ty + j][tx] = in[(size_t)(r0 + ty + j) * C + c0 + tx];
    __syncthreads();
#pragma unroll
    for (int j = 0; j < 32; j += 8)
        out[(size_t)(c0 + ty + j) * R + r0 + tx] = __float2bfloat16(t[tx][ty + j]);
}

// ---------------- GEMM: C[M][N] = A[M][K] * Bt[N][K]^T, bf16 in, MFMA 16x16x32 ----------------
// MODE 0: QKV epilogue (split q/k/v, q*=0.125, v transposed).  MODE 1: +bias, f32 out.
// R12: 256x128 tile, 8 waves (512 thr, 4m x 2n of 64x64), BK=64 SINGLE-buffered 48KB LDS,
// classic 2-barrier loop, launch_bounds(512,2) -> 16 waves/CU (2x R8).
// Rationale (R8..R11 ledger): barrier count per K dominates (R8 16 barriers = 97us beats
// R10's 64 = 103us and R11's 32 = 110us). So raise occupancy at FIXED barrier count by
// doubling waves per block; per-wave working set (64x64 acc, 16 ds_read+32 MFMA/K-tile,
// row&7 swizzle on 128B rows) is byte-identical to R8's verified config. m114: the 2nd
// resident block's waves compute while this block drains at the barrier.
// Grid: QKV 32x24=768 = exactly 3 rounds of 2 blocks/CU; XCD A-affinity preserved (bx%8).
template <int MODE>
__global__ __launch_bounds__(512, 2) void gemm_bt(
    const bf16* __restrict__ A, const bf16* __restrict__ Bt,
    int M, int N, int K,
    bf16* __restrict__ qo, bf16* __restrict__ ko, bf16* __restrict__ vto,
    float* __restrict__ out, const float* __restrict__ bias) {
    __shared__ __align__(16) bf16 Al[256 * 64];   // 32 KB
    __shared__ __align__(16) bf16 Bl[128 * 64];   // 16 KB
    const int tid = threadIdx.x;
    const int l = tid & 63, wid = tid >> 6;       // 8 waves
    const int lo = l & 15, hi = l >> 4;
    const int wm = wid & 3, wn = wid >> 2;        // 4m x 2n wave grid
    const int m0 = blockIdx.x * 256, n0 = blockIdx.y * 128;
    const int tsr = tid >> 3;                     // staging row 0..63
    const int tsc = tid & 7;                      // 16B chunk 0..7
    const int csw = (tsc ^ (tsr & 7)) * 8;        // pre-swizzled global col (elems)
    const int cl  = tsc * 8;                      // linear LDS col (elems)

    f32x4 acc[4][4];
#pragma unroll
    for (int i = 0; i < 4; ++i)
#pragma unroll
        for (int j = 0; j < 4; ++j) acc[i][j] = f32x4{0.f, 0.f, 0.f, 0.f};

    const int nkt = K / 64;
    for (int kt = 0; kt < nkt; ++kt) {
        // stage A (4 rows/thread) + B (2 rows/thread), both-sides swizzled
#pragma unroll
        for (int s = 0; s < 4; ++s) {
            int r = s * 64 + tsr;
            async16(A + (size_t)(m0 + r) * K + kt * 64 + csw, Al + r * 64 + cl);
        }
#pragma unroll
        for (int s = 0; s < 2; ++s) {
            int r = s * 64 + tsr;
            async16(Bt + (size_t)(n0 + r) * K + kt * 64 + csw, Bl + r * 64 + cl);
        }
        __syncthreads();   // vmcnt(0)+barrier: tile visible to all waves
        {
            bf16x8 af[4][2], bfv[4][2];
#pragma unroll
            for (int mt = 0; mt < 4; ++mt) {
                int ar = wm * 64 + mt * 16 + lo;
#pragma unroll
                for (int ks = 0; ks < 2; ++ks)
                    af[mt][ks] = load8bf(Al + ar * 64 + ((ks * 32 + hi * 8) ^ ((ar & 7) * 8)));
            }
#pragma unroll
            for (int nt = 0; nt < 4; ++nt) {
                int br = wn * 64 + nt * 16 + lo;
#pragma unroll
                for (int ks = 0; ks < 2; ++ks)
                    bfv[nt][ks] = load8bf(Bl + br * 64 + ((ks * 32 + hi * 8) ^ ((br & 7) * 8)));
            }
#pragma unroll
            for (int mt = 0; mt < 4; ++mt)
#pragma unroll
                for (int nt = 0; nt < 4; ++nt)
#pragma unroll
                    for (int ks = 0; ks < 2; ++ks)
                        acc[mt][nt] = __builtin_amdgcn_mfma_f32_16x16x32_bf16(
                            af[mt][ks], bfv[nt][ks], acc[mt][nt], 0, 0, 0);
        }
        __syncthreads();   // WAR: done reading before next stage overwrites
    }

#pragma unroll
    for (int mt = 0; mt < 4; ++mt)
#pragma unroll
        for (int nt = 0; nt < 4; ++nt)
#pragma unroll
            for (int r = 0; r < 4; ++r) {
                int row = m0 + wm * 64 + mt * 16 + hi * 4 + r;
                int col = n0 + wn * 64 + nt * 16 + lo;
                float v = acc[mt][nt][r];
                if (MODE == 0) {
                    if (col < 1024) {
                        qo[(size_t)row * 1024 + col] = __float2bfloat16(v * 0.125f);
                    } else if (col < 2048) {
                        ko[(size_t)row * 1024 + (col - 1024)] = __float2bfloat16(v);
                    } else {
                        int c = col - 2048;  // = h*64+d
                        vto[((size_t)(row >> 10) * 1024 + c) * 1024 + (row & 1023)] = __float2bfloat16(v);
                    }
                } else {
                    out[(size_t)row * N + col] = v + bias[col];
                }
            }
}

// ---------------- flash attention: grid = B*H*(N/128), 4 waves, 32 q-rows/wave ----------------
// (unchanged from R8: gload_lds double-buffer, XOR swizzle, no-max softmax, deferred l-sum)
__global__ __launch_bounds__(256, 3) void flash_attn(
    const bf16* __restrict__ q,    // [B*N][1024], q pre-scaled by 1/8
    const bf16* __restrict__ kin,  // [B*N][1024]
    const bf16* __restrict__ vt,   // [(b*1024 + h*64 + d)][1024] tokens
    bf16* __restrict__ out)        // [B*N][1024]
{
    __shared__ __align__(16) bf16 Kl0[64 * 64];
    __shared__ __align__(16) bf16 Vl0[64 * 64];
    __shared__ __align__(16) bf16 Kl1[64 * 64];
    __shared__ __align__(16) bf16 Vl1[64 * 64];
    __shared__ __align__(16) bf16 Pl[4 * 32 * 72];
    const int tid = threadIdx.x;
    const int l = tid & 63, w = tid >> 6;
    const int lo = l & 15, hi = l >> 4;
    const int bid = (blockIdx.x & 7) * 128 + (blockIdx.x >> 3);
    const int qt = bid & 7, h = (bid >> 3) & 15, b = bid >> 7;
    const int ts_r = tid >> 3;
    const int ts_c = tid & 7;
    const int ts_csw = (ts_c ^ (ts_r & 7)) * 8;
    const int ts_lds = tid * 8;

    const bf16* kbase = kin + (size_t)(b * 1024) * 1024 + h * 64;
    const bf16* vbase = vt + (size_t)(b * 1024 + h * 64) * 1024;

#define STAGE_KV(KD, VD, KT)                                                          \
    {                                                                                 \
        async16(kbase + (size_t)((KT) * 64 + ts_r) * 1024 + ts_csw, (KD) + ts_lds);   \
        async16(kbase + (size_t)((KT) * 64 + 32 + ts_r) * 1024 + ts_csw,              \
                (KD) + 2048 + ts_lds);                                                \
        async16(vbase + (size_t)ts_r * 1024 + (KT) * 64 + ts_csw, (VD) + ts_lds);     \
        async16(vbase + (size_t)(32 + ts_r) * 1024 + (KT) * 64 + ts_csw,              \
                (VD) + 2048 + ts_lds);                                                \
    }

    bf16x8 qf[2][2];
#pragma unroll
    for (int mt = 0; mt < 2; ++mt)
#pragma unroll
        for (int ks = 0; ks < 2; ++ks) {
            int tok = qt * 128 + w * 32 + mt * 16 + lo;
            qf[mt][ks] = load8bf(q + (size_t)(b * 1024 + tok) * 1024 + h * 64 + ks * 32 + hi * 8);
        }

    float lsum[2][4];
    f32x4 oacc[2][4];
#pragma unroll
    for (int mt = 0; mt < 2; ++mt)
#pragma unroll
        for (int r = 0; r < 4; ++r) lsum[mt][r] = 0.f;
#pragma unroll
    for (int mt = 0; mt < 2; ++mt)
#pragma unroll
        for (int nt = 0; nt < 4; ++nt) oacc[mt][nt] = f32x4{0.f, 0.f, 0.f, 0.f};

    STAGE_KV(Kl0, Vl0, 0)
    __syncthreads();

#define FA_ITER(KC, VC, KN, VN, KT, STG)                                              \
    {                                                                                 \
        if (STG) { STAGE_KV(KN, VN, (KT) + 1) }                                       \
        __builtin_amdgcn_sched_barrier(0);                                            \
        f32x4 s[2][4];                                                                \
        _Pragma("unroll") for (int mt = 0; mt < 2; ++mt)                              \
            _Pragma("unroll") for (int nt = 0; nt < 4; ++nt)                          \
                s[mt][nt] = f32x4{0.f, 0.f, 0.f, 0.f};                                \
        _Pragma("unroll") for (int ks = 0; ks < 2; ++ks) {                            \
            bf16x8 kf[4];                                                             \
            _Pragma("unroll") for (int nt = 0; nt < 4; ++nt) {                        \
                int kr = nt * 16 + lo;                                                \
                kf[nt] = load8bf((KC) + kr * 64 + ((ks * 32 + hi * 8) ^ ((kr & 7) * 8))); \
            }                                                                         \
            _Pragma("unroll") for (int mt = 0; mt < 2; ++mt)                          \
                _Pragma("unroll") for (int nt = 0; nt < 4; ++nt)                      \
                    s[mt][nt] = __builtin_amdgcn_mfma_f32_16x16x32_bf16(              \
                        qf[mt][ks], kf[nt], s[mt][nt], 0, 0, 0);                      \
        }                                                                             \
        _Pragma("unroll") for (int mt = 0; mt < 2; ++mt)                              \
            _Pragma("unroll") for (int nt = 0; nt < 4; ++nt)                          \
                _Pragma("unroll") for (int r = 0; r < 4; ++r) {                       \
                    float p = __expf(s[mt][nt][r]);                                   \
                    lsum[mt][r] += p;                                                 \
                    Pl[(w * 32 + mt * 16 + hi * 4 + r) * 72 + nt * 16 + lo] =         \
                        __float2bfloat16(p);                                          \
                }                                                                     \
        _Pragma("unroll") for (int ks = 0; ks < 2; ++ks) {                            \
            bf16x8 vf[4], pf[2];                                                      \
            _Pragma("unroll") for (int nt = 0; nt < 4; ++nt) {                        \
                int vr = nt * 16 + lo;                                                \
                vf[nt] = load8bf((VC) + vr * 64 + ((ks * 32 + hi * 8) ^ ((vr & 7) * 8))); \
            }                                                                         \
            _Pragma("unroll") for (int mt = 0; mt < 2; ++mt)                          \
                pf[mt] = load8bf(Pl + (w * 32 + mt * 16 + lo) * 72 + ks * 32 + hi * 8); \
            _Pragma("unroll") for (int mt = 0; mt < 2; ++mt)                          \
                _Pragma("unroll") for (int nt = 0; nt < 4; ++nt)                      \
                    oacc[mt][nt] = __builtin_amdgcn_mfma_f32_16x16x32_bf16(           \
                        pf[mt], vf[nt], oacc[mt][nt], 0, 0, 0);                       \
        }                                                                             \
        __syncthreads();                                                              \
    }

    for (int kt = 0; kt < 16; kt += 2) {
        FA_ITER(Kl0, Vl0, Kl1, Vl1, kt, true)
        FA_ITER(Kl1, Vl1, Kl0, Vl0, kt + 1, (kt + 2 < 16))
    }
#undef FA_ITER
#undef STAGE_KV

#pragma unroll
    for (int mt = 0; mt < 2; ++mt)
#pragma unroll
        for (int r = 0; r < 4; ++r) {
#pragma unroll
            for (int off = 1; off < 16; off <<= 1)
                lsum[mt][r] += __shfl_xor(lsum[mt][r], off);
        }

#pragma unroll
    for (int mt = 0; mt < 2; ++mt)
#pragma unroll
        for (int nt = 0; nt < 4; ++nt)
#pragma unroll
            for (int r = 0; r < 4; ++r) {
                int tok = qt * 128 + w * 32 + mt * 16 + hi * 4 + r;
                int d = nt * 16 + lo;
                out[(size_t)(b * 1024 + tok) * 1024 + h * 64 + d] =
                    __float2bfloat16(oacc[mt][nt][r] / lsum[mt][r]);
            }
}

extern "C" void kernel_launch(void* const* d_in, const int* in_sizes, int n_in,
                              void* d_out, int out_size, void* d_ws, size_t ws_size,
                              hipStream_t stream) {
    const float* x      = (const float*)d_in[0];
    const float* w_qkv  = (const float*)d_in[1];
    const float* w_proj = (const float*)d_in[2];
    const float* b_proj = (const float*)d_in[3];
    float* out = (float*)d_out;   // reference output dtype is float32

    char* ws = (char*)d_ws;
    bf16* xb     = (bf16*)(ws);                       // 16 MB [8192][1024]; reused as attn out
    bf16* wqkvT  = (bf16*)(ws + (16ull << 20));       //  6 MB [3072][1024]
    bf16* wprojT = (bf16*)(ws + (22ull << 20));       //  2 MB [1024][1024]
    bf16* qb     = (bf16*)(ws + (24ull << 20));       // 16 MB
    bf16* kb     = (bf16*)(ws + (40ull << 20));       // 16 MB
    bf16* vtb    = (bf16*)(ws + (56ull << 20));       // 16 MB  [b*1024 + h*64+d][1024]
    bf16* attn   = xb;                                // reuse (xb dead after QKV GEMM)

    cast_x_kernel<<<8192, 256, 0, stream>>>(x, xb, 2 * 1024 * 1024);
    transpose_cast<<<dim3(96, 32), dim3(32, 8), 0, stream>>>(w_qkv, wqkvT, 1024, 3072);
    transpose_cast<<<dim3(32, 32), dim3(32, 8), 0, stream>>>(w_proj, wprojT, 1024, 1024);
    gemm_bt<0><<<dim3(32, 24), 512, 0, stream>>>(xb, wqkvT, 8192, 3072, 1024,
                                                 qb, kb, vtb, nullptr, nullptr);
    flash_attn<<<1024, 256, 0, stream>>>(qb, kb, vtb, attn);
    gemm_bt<1><<<dim3(32, 8), 512, 0, stream>>>(attn, wprojT, 8192, 1024, 1024,
                                                nullptr, nullptr, nullptr, out, b_proj);
}